// Round 2
// baseline (239.297 us; speedup 1.0000x reference)
//
#include <hip/hip_runtime.h>

#define DM 1024
#define NH 16
#define DK 64
#define BB 2
#define SS 2048

typedef unsigned short u16;
typedef unsigned int   u32;
typedef __bf16 bf16x8 __attribute__((ext_vector_type(8)));
typedef float  f32x4  __attribute__((ext_vector_type(4)));

__device__ __forceinline__ u16 f2bf(float f){
  u32 u = __float_as_uint(f);
  u32 r = (u + 0x7FFFu + ((u >> 16) & 1u)) >> 16;   // RNE
  return (u16)r;
}
__device__ __forceinline__ float bf2f(u16 v){ return __uint_as_float(((u32)v) << 16); }

__device__ __forceinline__ void gl16(const void* g, void* l){
  __builtin_amdgcn_global_load_lds((const __attribute__((address_space(1))) u32*)g,
                                   (__attribute__((address_space(3))) u32*)l, 16, 0, 0);
}
__device__ __forceinline__ f32x4 mfma16(bf16x8 a, bf16x8 b, f32x4 c){
  return __builtin_amdgcn_mfma_f32_16x16x32_bf16(a, b, c, 0, 0, 0);
}

// ---------------- casts ----------------
__global__ void k_cast_x(const float* __restrict__ s, u16* __restrict__ d){
  int i = (blockIdx.x*256 + threadIdx.x)*4;
  float4 v = *(const float4*)(s+i);
  u32 lo = (u32)f2bf(v.x) | ((u32)f2bf(v.y) << 16);
  u32 hi = (u32)f2bf(v.z) | ((u32)f2bf(v.w) << 16);
  uint2 t; t.x = lo; t.y = hi;
  *(uint2*)(d+i) = t;
}

__global__ void k_cast_w(const float* a, const float* b, const float* c, const float* dd,
                         u16* __restrict__ dst){
  const float* srcs[4] = {a,b,c,dd};
  const float* s = srcs[blockIdx.y];
  u16* o = dst + ((size_t)blockIdx.y << 20);
  int i = (blockIdx.x*256 + threadIdx.x)*4;
  float4 v = *(const float4*)(s+i);
  u32 lo = (u32)f2bf(v.x) | ((u32)f2bf(v.y) << 16);
  u32 hi = (u32)f2bf(v.z) | ((u32)f2bf(v.w) << 16);
  uint2 t; t.x = lo; t.y = hi;
  *(uint2*)(o+i) = t;
}

// ---------------- GEMM core: C[m][n] = sum_k A[m][k] * B[n][k]  (B given row-major [N][K]) ----
// 128x128 tile, BK=64, 256 threads = 4 waves, each wave 64x64 (4x4 frags of 16x16x32 MFMA).
__device__ __forceinline__ void gemm_core(const u16* __restrict__ A, const u16* __restrict__ Bw,
                                          u16* As, u16* Bs, f32x4 (&acc)[4][4]){
  const int tid = threadIdx.x, lane = tid & 63, wid = tid >> 6;
  const int m0 = blockIdx.y * 128, n0 = blockIdx.x * 128;
  const int wm = (wid >> 1) * 64, wn = (wid & 1) * 64;
  for (int k0 = 0; k0 < DM; k0 += 64){
    __syncthreads();          // protect LDS vs previous iteration readers
    #pragma unroll
    for (int i = 0; i < 4; i++){
      int row = i*32 + (tid >> 3);
      int cb  = (tid & 7) * 8;
      gl16(A  + (size_t)(m0+row)*DM + k0 + cb, (char*)As + i*4096 + tid*16);
      gl16(Bw + (size_t)(n0+row)*DM + k0 + cb, (char*)Bs + i*4096 + tid*16);
    }
    __syncthreads();          // drains vmcnt for global_load_lds
    #pragma unroll
    for (int kk = 0; kk < 2; kk++){
      const int co = kk*64 + (lane >> 4) * 16;   // byte offset along K within row
      bf16x8 af[4], bfr[4];
      #pragma unroll
      for (int mi = 0; mi < 4; mi++)
        af[mi] = *(const bf16x8*)((const char*)As + (wm + mi*16 + (lane & 15))*128 + co);
      #pragma unroll
      for (int ni = 0; ni < 4; ni++)
        bfr[ni] = *(const bf16x8*)((const char*)Bs + (wn + ni*16 + (lane & 15))*128 + co);
      #pragma unroll
      for (int mi = 0; mi < 4; mi++)
        #pragma unroll
        for (int ni = 0; ni < 4; ni++)
          acc[mi][ni] = mfma16(af[mi], bfr[ni], acc[mi][ni]);
    }
  }
}

__global__ __launch_bounds__(256) void k_gemm_qkv(const u16* __restrict__ xb, const u16* __restrict__ Wb,
                                                  u16* __restrict__ Qb, u16* __restrict__ Kb,
                                                  u16* __restrict__ Vb){
  __shared__ __align__(16) u16 As[8192];
  __shared__ __align__(16) u16 Bs[8192];
  const int z = blockIdx.z;
  const u16* Bw = Wb + ((size_t)z << 20);
  u16* C = (z == 0) ? Qb : ((z == 1) ? Kb : Vb);
  f32x4 acc[4][4] = {};
  gemm_core(xb, Bw, As, Bs, acc);
  const int lane = threadIdx.x & 63, wid = threadIdx.x >> 6;
  const int m0 = blockIdx.y*128 + (wid >> 1)*64, n0 = blockIdx.x*128 + (wid & 1)*64;
  #pragma unroll
  for (int mi = 0; mi < 4; mi++)
    #pragma unroll
    for (int ni = 0; ni < 4; ni++)
      #pragma unroll
      for (int r = 0; r < 4; r++){
        int m = m0 + mi*16 + (lane >> 4)*4 + r;
        int n = n0 + ni*16 + (lane & 15);
        C[(size_t)m*DM + n] = f2bf(acc[mi][ni][r]);
      }
}

__global__ __launch_bounds__(256) void k_gemm_out(const u16* __restrict__ AO, const u16* __restrict__ Wo,
                                                  float* __restrict__ Co){
  __shared__ __align__(16) u16 As[8192];
  __shared__ __align__(16) u16 Bs[8192];
  f32x4 acc[4][4] = {};
  gemm_core(AO, Wo, As, Bs, acc);
  const int lane = threadIdx.x & 63, wid = threadIdx.x >> 6;
  const int m0 = blockIdx.y*128 + (wid >> 1)*64, n0 = blockIdx.x*128 + (wid & 1)*64;
  #pragma unroll
  for (int mi = 0; mi < 4; mi++)
    #pragma unroll
    for (int ni = 0; ni < 4; ni++)
      #pragma unroll
      for (int r = 0; r < 4; r++){
        int m = m0 + mi*16 + (lane >> 4)*4 + r;
        int n = n0 + ni*16 + (lane & 15);
        Co[(size_t)m*DM + n] = acc[mi][ni][r];
      }
}

// ---------------- RoPE (in place on bf16 Q and K) ----------------
// pair p = row*512 + h*32 + j; elements (2p, 2p+1) form the interleaved pair.
// NOTE: sincosf outputs SIN FIRST. Precise (non-__) version: valid for all arg
// magnitudes (v_sin_f32 domain is only ~±256 revolutions; pos*inv reaches 326).
__global__ void k_rope(u16* __restrict__ Q, u16* __restrict__ K, const int* __restrict__ pos){
  int p = blockIdx.x*256 + threadIdx.x;
  int row = p >> 9;                       // b*S + s
  int j = p & 31;
  float pf = (float)pos[row & (SS-1)];
  // theta^(-2j/64) = 2^(-j*log2(1e4)/32)
  float inv = exp2f(-0.4152410118609203f * (float)j);
  float s, c;
  sincosf(pf * inv, &s, &c);
  u32* T = (u32*)(blockIdx.y ? K : Q);
  u32 e = T[p];
  float x0 = bf2f((u16)(e & 0xffff)), x1 = bf2f((u16)(e >> 16));
  float o0 = x0*c - x1*s;
  float o1 = x0*s + x1*c;
  T[p] = (u32)f2bf(o0) | ((u32)f2bf(o1) << 16);
}

// ---------------- flash attention, causal ----------------
// block = (b,h,qtile of 64). 4 waves x 16 q-rows. K tile [64][64] LDS (XOR-swizzled via
// pre-swizzled global source for global_load_lds); V staged transposed [d][kv] with swizzle;
// P round-trips through per-wave swizzled LDS to convert C-layout -> A-layout.
__global__ __launch_bounds__(256) void k_attn(const u16* __restrict__ Q, const u16* __restrict__ K,
                                              const u16* __restrict__ V, u16* __restrict__ AO){
  __shared__ __align__(16) u16 Ks[64*64];
  __shared__ __align__(16) u16 Vt[64*64];
  __shared__ __align__(16) u16 Ps[4][16*64];
  const int tid = threadIdx.x, lane = tid & 63, wid = tid >> 6;
  const int qt = blockIdx.x, h = blockIdx.y, b = blockIdx.z;
  const int q0 = qt*64, qw = q0 + wid*16;
  const size_t base = ((size_t)b*SS)*DM + (size_t)h*DK;

  const int qrow = qw + (lane & 15);
  bf16x8 qf0 = *(const bf16x8*)(Q + base + (size_t)qrow*DM +      (lane >> 4)*8);
  bf16x8 qf1 = *(const bf16x8*)(Q + base + (size_t)qrow*DM + 32 + (lane >> 4)*8);

  f32x4 oacc[4] = {};
  float mrow[4] = {-3e38f,-3e38f,-3e38f,-3e38f};
  float lrow[4] = {0.f,0.f,0.f,0.f};

  for (int kt = 0; kt <= qt; kt++){
    const int kv0 = kt*64;
    __syncthreads();                     // previous tile fully consumed
    #pragma unroll
    for (int i = 0; i < 2; i++){         // K: 2 issues x 256 thr x 16B = 8KB
      int L = i*4096 + tid*16;
      int kv = L >> 7;
      int inner = (L & 127) ^ ((kv & 7) << 4);   // pre-swizzle source so LDS read is XOR-swizzled
      gl16(K + base + (size_t)(kv0+kv)*DM + (inner >> 1), (char*)Ks + L);
    }
    {                                    // V transposed: [d][kv], packed b32 writes, swizzled
      const int dbase = (tid >> 5)*8, kvl = (tid & 31)*2;
      const u16* vsrc = V + base + (size_t)(kv0+kvl)*DM + dbase;
      bf16x8 r0 = *(const bf16x8*)(vsrc);
      bf16x8 r1 = *(const bf16x8*)(vsrc + DM);
      const u16* p0 = (const u16*)&r0; const u16* p1 = (const u16*)&r1;
      #pragma unroll
      for (int j = 0; j < 8; j++){
        int d = dbase + j;
        int byteoff = (d*128 + kvl*2) ^ ((d & 7) << 4);
        *(u32*)((char*)Vt + byteoff) = (u32)p0[j] | ((u32)p1[j] << 16);
      }
    }
    __syncthreads();

    // QK^T : S[q][kv], 4 kv-subtiles x 2 k-steps
    f32x4 sf[4] = {};
    #pragma unroll
    for (int kk = 0; kk < 2; kk++){
      const int co = kk*64 + (lane >> 4)*16;
      #pragma unroll
      for (int f = 0; f < 4; f++){
        int kvr = f*16 + (lane & 15);
        bf16x8 kf = *(const bf16x8*)((const char*)Ks + ((kvr*128 + co) ^ ((kvr & 7) << 4)));
        sf[f] = mfma16(kk ? qf1 : qf0, kf, sf[f]);
      }
    }

    // online softmax (row stats across 16 lanes of kv) + P -> LDS (bf16, swizzled)
    #pragma unroll
    for (int r = 0; r < 4; r++){
      const int qa = qw + (lane >> 4)*4 + r;
      float sc[4]; float mx = -3e38f;
      #pragma unroll
      for (int f = 0; f < 4; f++){
        float s = sf[f][r] * 0.125f;            // 1/sqrt(64)
        int kva = kv0 + f*16 + (lane & 15);
        s = (kva <= qa) ? s : -3e38f;
        sc[f] = s;
        mx = fmaxf(mx, s);
      }
      #pragma unroll
      for (int d = 1; d < 16; d <<= 1) mx = fmaxf(mx, __shfl_xor(mx, d));
      const float mn = fmaxf(mrow[r], mx);
      const float alpha = __expf(mrow[r] - mn);
      float psum = 0.f;
      #pragma unroll
      for (int f = 0; f < 4; f++){ float pv = __expf(sc[f] - mn); sc[f] = pv; psum += pv; }
      #pragma unroll
      for (int d = 1; d < 16; d <<= 1) psum += __shfl_xor(psum, d);
      lrow[r] = lrow[r]*alpha + psum;
      mrow[r] = mn;
      #pragma unroll
      for (int ni = 0; ni < 4; ni++) oacc[ni][r] *= alpha;
      const int prow = (lane >> 4)*4 + r;
      #pragma unroll
      for (int f = 0; f < 4; f++){
        int byteoff = (prow*128 + (f*16 + (lane & 15))*2) ^ ((prow & 7) << 4);
        *(u16*)((char*)Ps[wid] + byteoff) = f2bf(sc[f]);
      }
    }

    // PV : O[q][d] += P[q][kv] * V[kv][d]
    #pragma unroll
    for (int kk = 0; kk < 2; kk++){
      const int pr = lane & 15;
      bf16x8 pf = *(const bf16x8*)((const char*)Ps[wid] +
                    ((pr*128 + kk*64 + (lane >> 4)*16) ^ ((pr & 7) << 4)));
      #pragma unroll
      for (int ni = 0; ni < 4; ni++){
        int d = ni*16 + (lane & 15);
        bf16x8 vf = *(const bf16x8*)((const char*)Vt +
                      ((d*128 + kk*64 + (lane >> 4)*16) ^ ((d & 7) << 4)));
        oacc[ni] = mfma16(pf, vf, oacc[ni]);
      }
    }
  }

  #pragma unroll
  for (int ni = 0; ni < 4; ni++)
    #pragma unroll
    for (int r = 0; r < 4; r++){
      int qa = qw + (lane >> 4)*4 + r;
      float v = oacc[ni][r] / lrow[r];
      AO[base + (size_t)qa*DM + ni*16 + (lane & 15)] = f2bf(v);
    }
}

// ---------------- launch ----------------
extern "C" void kernel_launch(void* const* d_in, const int* in_sizes, int n_in,
                              void* d_out, int out_size, void* d_ws, size_t ws_size,
                              hipStream_t stream){
  const float* x   = (const float*)d_in[0];
  const float* Wq  = (const float*)d_in[1];
  const float* Wk  = (const float*)d_in[2];
  const float* Wv  = (const float*)d_in[3];
  const float* Wo  = (const float*)d_in[4];
  const int*   pos = (const int*)d_in[5];
  float* out = (float*)d_out;

  const size_t NEED = (size_t)40 << 20;   // 40 MiB
  if (ws_size < NEED){
    // loud failure sentinel: fill output with ~3.4e38 so the bench distinguishes
    // "workspace too small" from a numerics bug.
    hipMemsetAsync(d_out, 0x7f, (size_t)out_size * sizeof(float), stream);
    return;
  }

  char* ws = (char*)d_ws;
  u16* xb = (u16*)(ws);                   // 8 MiB: x bf16 [4096][1024]
  u16* Wb = (u16*)(ws + ((size_t)8  << 20)); // 8 MiB: Wq,Wk,Wv,Wo bf16
  u16* Qb = (u16*)(ws + ((size_t)16 << 20)); // 8 MiB
  u16* Kb = (u16*)(ws + ((size_t)24 << 20)); // 8 MiB
  u16* Vb = (u16*)(ws + ((size_t)32 << 20)); // 8 MiB
  u16* AO = xb;                            // alias: xb dead after QKV GEMM

  k_cast_x<<<4096, 256, 0, stream>>>(x, xb);
  k_cast_w<<<dim3(1024, 4), 256, 0, stream>>>(Wq, Wk, Wv, Wo, Wb);
  k_gemm_qkv<<<dim3(8, 32, 3), 256, 0, stream>>>(xb, Wb, Qb, Kb, Vb);
  k_rope<<<dim3(8192, 2), 256, 0, stream>>>(Qb, Kb, pos);
  k_attn<<<dim3(32, 16, 2), 256, 0, stream>>>(Qb, Kb, Vb, AO);
  k_gemm_out<<<dim3(8, 32), 256, 0, stream>>>(AO, Wb + ((size_t)3 << 20), out);
}

// Round 3
// 213.800 us; speedup vs baseline: 1.1193x; 1.1193x over previous
//
#include <hip/hip_runtime.h>

#define DM 1024
#define NH 16
#define DK 64
#define BB 2
#define SS 2048

typedef unsigned short u16;
typedef unsigned int   u32;
typedef __bf16 bf16x8 __attribute__((ext_vector_type(8)));
typedef float  f32x4  __attribute__((ext_vector_type(4)));

__device__ __forceinline__ u16 f2bf(float f){
  u32 u = __float_as_uint(f);
  u32 r = (u + 0x7FFFu + ((u >> 16) & 1u)) >> 16;   // RNE
  return (u16)r;
}
__device__ __forceinline__ float bf2f(u16 v){ return __uint_as_float(((u32)v) << 16); }

__device__ __forceinline__ void gl16(const void* g, void* l){
  __builtin_amdgcn_global_load_lds((const __attribute__((address_space(1))) u32*)g,
                                   (__attribute__((address_space(3))) u32*)l, 16, 0, 0);
}
__device__ __forceinline__ f32x4 mfma16(bf16x8 a, bf16x8 b, f32x4 c){
  return __builtin_amdgcn_mfma_f32_16x16x32_bf16(a, b, c, 0, 0, 0);
}

// ---------------- casts ----------------
__global__ void k_cast_x(const float* __restrict__ s, u16* __restrict__ d){
  int i = (blockIdx.x*256 + threadIdx.x)*4;
  float4 v = *(const float4*)(s+i);
  u32 lo = (u32)f2bf(v.x) | ((u32)f2bf(v.y) << 16);
  u32 hi = (u32)f2bf(v.z) | ((u32)f2bf(v.w) << 16);
  uint2 t; t.x = lo; t.y = hi;
  *(uint2*)(d+i) = t;
}

__global__ void k_cast_w(const float* a, const float* b, const float* c, const float* dd,
                         u16* __restrict__ dst){
  const float* srcs[4] = {a,b,c,dd};
  const float* s = srcs[blockIdx.y];
  u16* o = dst + ((size_t)blockIdx.y << 20);
  int i = (blockIdx.x*256 + threadIdx.x)*4;
  float4 v = *(const float4*)(s+i);
  u32 lo = (u32)f2bf(v.x) | ((u32)f2bf(v.y) << 16);
  u32 hi = (u32)f2bf(v.z) | ((u32)f2bf(v.w) << 16);
  uint2 t; t.x = lo; t.y = hi;
  *(uint2*)(o+i) = t;
}

// ---------------- GEMM core (unchanged, verified) ----------------
__device__ __forceinline__ void gemm_core(const u16* __restrict__ A, const u16* __restrict__ Bw,
                                          u16* As, u16* Bs, f32x4 (&acc)[4][4]){
  const int tid = threadIdx.x, lane = tid & 63, wid = tid >> 6;
  const int m0 = blockIdx.y * 128, n0 = blockIdx.x * 128;
  const int wm = (wid >> 1) * 64, wn = (wid & 1) * 64;
  for (int k0 = 0; k0 < DM; k0 += 64){
    __syncthreads();
    #pragma unroll
    for (int i = 0; i < 4; i++){
      int row = i*32 + (tid >> 3);
      int cb  = (tid & 7) * 8;
      gl16(A  + (size_t)(m0+row)*DM + k0 + cb, (char*)As + i*4096 + tid*16);
      gl16(Bw + (size_t)(n0+row)*DM + k0 + cb, (char*)Bs + i*4096 + tid*16);
    }
    __syncthreads();
    #pragma unroll
    for (int kk = 0; kk < 2; kk++){
      const int co = kk*64 + (lane >> 4) * 16;
      bf16x8 af[4], bfr[4];
      #pragma unroll
      for (int mi = 0; mi < 4; mi++)
        af[mi] = *(const bf16x8*)((const char*)As + (wm + mi*16 + (lane & 15))*128 + co);
      #pragma unroll
      for (int ni = 0; ni < 4; ni++)
        bfr[ni] = *(const bf16x8*)((const char*)Bs + (wn + ni*16 + (lane & 15))*128 + co);
      #pragma unroll
      for (int mi = 0; mi < 4; mi++)
        #pragma unroll
        for (int ni = 0; ni < 4; ni++)
          acc[mi][ni] = mfma16(af[mi], bfr[ni], acc[mi][ni]);
    }
  }
}

__global__ __launch_bounds__(256) void k_gemm_qkv(const u16* __restrict__ xb, const u16* __restrict__ Wb,
                                                  u16* __restrict__ Qb, u16* __restrict__ Kb,
                                                  u16* __restrict__ Vb){
  __shared__ __align__(16) u16 As[8192];
  __shared__ __align__(16) u16 Bs[8192];
  const int z = blockIdx.z;
  const u16* Bw = Wb + ((size_t)z << 20);
  u16* C = (z == 0) ? Qb : ((z == 1) ? Kb : Vb);
  f32x4 acc[4][4] = {};
  gemm_core(xb, Bw, As, Bs, acc);
  const int lane = threadIdx.x & 63, wid = threadIdx.x >> 6;
  const int m0 = blockIdx.y*128 + (wid >> 1)*64, n0 = blockIdx.x*128 + (wid & 1)*64;
  #pragma unroll
  for (int mi = 0; mi < 4; mi++)
    #pragma unroll
    for (int ni = 0; ni < 4; ni++)
      #pragma unroll
      for (int r = 0; r < 4; r++){
        int m = m0 + mi*16 + (lane >> 4)*4 + r;
        int n = n0 + ni*16 + (lane & 15);
        C[(size_t)m*DM + n] = f2bf(acc[mi][ni][r]);
      }
}

__global__ __launch_bounds__(256) void k_gemm_out(const u16* __restrict__ AO, const u16* __restrict__ Wo,
                                                  float* __restrict__ Co){
  __shared__ __align__(16) u16 As[8192];
  __shared__ __align__(16) u16 Bs[8192];
  f32x4 acc[4][4] = {};
  gemm_core(AO, Wo, As, Bs, acc);
  const int lane = threadIdx.x & 63, wid = threadIdx.x >> 6;
  const int m0 = blockIdx.y*128 + (wid >> 1)*64, n0 = blockIdx.x*128 + (wid & 1)*64;
  #pragma unroll
  for (int mi = 0; mi < 4; mi++)
    #pragma unroll
    for (int ni = 0; ni < 4; ni++)
      #pragma unroll
      for (int r = 0; r < 4; r++){
        int m = m0 + mi*16 + (lane >> 4)*4 + r;
        int n = n0 + ni*16 + (lane & 15);
        Co[(size_t)m*DM + n] = acc[mi][ni][r];
      }
}

// ---------------- RoPE (unchanged, verified) ----------------
__global__ void k_rope(u16* __restrict__ Q, u16* __restrict__ K, const int* __restrict__ pos){
  int p = blockIdx.x*256 + threadIdx.x;
  int row = p >> 9;
  int j = p & 31;
  float pf = (float)pos[row & (SS-1)];
  float inv = exp2f(-0.4152410118609203f * (float)j);
  float s, c;
  sincosf(pf * inv, &s, &c);
  u32* T = (u32*)(blockIdx.y ? K : Q);
  u32 e = T[p];
  float x0 = bf2f((u16)(e & 0xffff)), x1 = bf2f((u16)(e >> 16));
  float o0 = x0*c - x1*s;
  float o1 = x0*s + x1*c;
  T[p] = (u32)f2bf(o0) | ((u32)f2bf(o1) << 16);
}

// ---------------- flash attention, causal, swapped-operand softmax ----------------
// Swapped QK^T: sf = mfma(K,Q) -> S[kv][q] with q = lane&15 per lane: row-reduce is
// in-lane tree + 2 shuffles. Swapped PV: mfma(V,P) -> O[d][q], q = lane&15: rescale
// and 1/l are per-lane scalars, no broadcasts. LDS double-buffered, one barrier/iter,
// next-tile staging issued before compute (latency hidden under MFMA/softmax).
__global__ __launch_bounds__(256) void k_attn(const u16* __restrict__ Q, const u16* __restrict__ K,
                                              const u16* __restrict__ V, u16* __restrict__ AO){
  __shared__ __align__(16) u16 Ks[2][64*64];
  __shared__ __align__(16) u16 Vt[2][64*64];
  __shared__ __align__(16) u16 Ps[4][16*64];
  const int tid = threadIdx.x, lane = tid & 63, wid = tid >> 6;
  const int qt = (int)gridDim.x - 1 - blockIdx.x;   // longest blocks dispatch first
  const int h = blockIdx.y, b = blockIdx.z;
  const int q0 = qt*64, qw = q0 + wid*16;
  const size_t base = ((size_t)b*SS)*DM + (size_t)h*DK;
  const int ql = lane & 15, lg = lane >> 4;

  const u16* qptr = Q + base + (size_t)(qw + ql)*DM + lg*8;
  bf16x8 qf0 = *(const bf16x8*)(qptr);
  bf16x8 qf1 = *(const bf16x8*)(qptr + 32);

  f32x4 oacc[4] = {};
  float m = -3e38f, lsum = 0.f;
  const float SC = 0.125f * 1.4426950408889634f;   // 1/sqrt(64) * log2(e)

  const int dbase = (tid >> 5)*8, kvl = (tid & 31)*2;

  // ---- prologue: stage tile 0 ----
  #pragma unroll
  for (int i = 0; i < 2; i++){
    int L = i*4096 + tid*16;
    int kv = L >> 7;
    int inner = (L & 127) ^ ((kv & 7) << 4);
    gl16(K + base + (size_t)kv*DM + (inner >> 1), (char*)Ks[0] + L);
  }
  {
    const u16* vsrc = V + base + (size_t)kvl*DM + dbase;
    bf16x8 r0 = *(const bf16x8*)(vsrc);
    bf16x8 r1 = *(const bf16x8*)(vsrc + DM);
    const u16* p0 = (const u16*)&r0; const u16* p1 = (const u16*)&r1;
    #pragma unroll
    for (int j = 0; j < 8; j++){
      int d = dbase + j;
      int byteoff = (d*128 + kvl*2) ^ ((d & 7) << 4);
      *(u32*)((char*)Vt[0] + byteoff) = (u32)p0[j] | ((u32)p1[j] << 16);
    }
  }
  __syncthreads();

  int cur = 0;
  for (int kt = 0; kt <= qt; kt++){
    const int kv0 = kt*64;
    const bool more = (kt < qt);
    bf16x8 vr0, vr1;
    if (more){
      const int kn0 = kv0 + 64;
      #pragma unroll
      for (int i = 0; i < 2; i++){
        int L = i*4096 + tid*16;
        int kv = L >> 7;
        int inner = (L & 127) ^ ((kv & 7) << 4);
        gl16(K + base + (size_t)(kn0+kv)*DM + (inner >> 1), (char*)Ks[cur^1] + L);
      }
      const u16* vsrc = V + base + (size_t)(kn0+kvl)*DM + dbase;
      vr0 = *(const bf16x8*)(vsrc);
      vr1 = *(const bf16x8*)(vsrc + DM);
    }

    // QK^T swapped: sf[f][r] = S[kv0 + f*16 + lg*4 + r][qw + ql] * (unscaled)
    f32x4 sf[4] = {};
    #pragma unroll
    for (int kk = 0; kk < 2; kk++){
      const int co = kk*64 + lg*16;
      #pragma unroll
      for (int f = 0; f < 4; f++){
        int kvr = f*16 + ql;
        bf16x8 kf = *(const bf16x8*)((const char*)Ks[cur] + ((kvr*128 + co) ^ ((kvr & 7) << 4)));
        sf[f] = mfma16(kf, kk ? qf1 : qf0, sf[f]);
      }
    }

    // scale (+ mask only on diagonal tile), log2 domain
    float sc[4][4];
    if (kt == qt){
      const int qa = qw + ql;
      #pragma unroll
      for (int f = 0; f < 4; f++)
        #pragma unroll
        for (int r = 0; r < 4; r++){
          int kva = kv0 + f*16 + lg*4 + r;
          sc[f][r] = (kva <= qa) ? sf[f][r]*SC : -3e38f;
        }
    } else {
      #pragma unroll
      for (int f = 0; f < 4; f++)
        #pragma unroll
        for (int r = 0; r < 4; r++)
          sc[f][r] = sf[f][r]*SC;
    }

    float mxp[4];
    #pragma unroll
    for (int r = 0; r < 4; r++)
      mxp[r] = fmaxf(fmaxf(sc[0][r], sc[1][r]), fmaxf(sc[2][r], sc[3][r]));
    float mx = fmaxf(fmaxf(mxp[0], mxp[1]), fmaxf(mxp[2], mxp[3]));
    mx = fmaxf(mx, __shfl_xor(mx, 16));
    mx = fmaxf(mx, __shfl_xor(mx, 32));
    const float mn = fmaxf(m, mx);
    const float alpha = exp2f(m - mn);
    #pragma unroll
    for (int f = 0; f < 4; f++)
      #pragma unroll
      for (int r = 0; r < 4; r++)
        sc[f][r] = exp2f(sc[f][r] - mn);
    float ps[4];
    #pragma unroll
    for (int r = 0; r < 4; r++)
      ps[r] = (sc[0][r]+sc[1][r]) + (sc[2][r]+sc[3][r]);
    float psum = (ps[0]+ps[1]) + (ps[2]+ps[3]);
    psum += __shfl_xor(psum, 16);
    psum += __shfl_xor(psum, 32);
    lsum = lsum*alpha + psum;
    m = mn;
    #pragma unroll
    for (int ni = 0; ni < 4; ni++) oacc[ni] *= alpha;

    // store P (pack r pairs): P[q=ql][kv = f*16 + lg*4 + r]
    #pragma unroll
    for (int f = 0; f < 4; f++)
      #pragma unroll
      for (int r = 0; r < 4; r += 2){
        int kv = f*16 + lg*4 + r;
        int byteoff = (ql*128 + kv*2) ^ ((ql & 7) << 4);
        *(u32*)((char*)Ps[wid] + byteoff) = (u32)f2bf(sc[f][r]) | ((u32)f2bf(sc[f][r+1]) << 16);
      }

    // PV swapped: oacc[ni][r] = O[q=ql][d = ni*16 + lg*4 + r]
    #pragma unroll
    for (int kk = 0; kk < 2; kk++){
      bf16x8 pf = *(const bf16x8*)((const char*)Ps[wid] +
                    ((ql*128 + kk*64 + lg*16) ^ ((ql & 7) << 4)));
      #pragma unroll
      for (int ni = 0; ni < 4; ni++){
        int d = ni*16 + ql;
        bf16x8 vf = *(const bf16x8*)((const char*)Vt[cur] +
                      ((d*128 + kk*64 + lg*16) ^ ((d & 7) << 4)));
        oacc[ni] = mfma16(vf, pf, oacc[ni]);
      }
    }

    if (more){
      const u16* p0 = (const u16*)&vr0; const u16* p1 = (const u16*)&vr1;
      #pragma unroll
      for (int j = 0; j < 8; j++){
        int d = dbase + j;
        int byteoff = (d*128 + kvl*2) ^ ((d & 7) << 4);
        *(u32*)((char*)Vt[cur^1] + byteoff) = (u32)p0[j] | ((u32)p1[j] << 16);
      }
    }
    __syncthreads();
    cur ^= 1;
  }

  // epilogue: O^T -> per-wave LDS -> coalesced global
  const float rl = 1.0f / lsum;
  #pragma unroll
  for (int ni = 0; ni < 4; ni++)
    #pragma unroll
    for (int r = 0; r < 4; r += 2){
      int d = ni*16 + lg*4 + r;
      int byteoff = (ql*128 + d*2) ^ ((ql & 7) << 4);
      *(u32*)((char*)Ps[wid] + byteoff) =
        (u32)f2bf(oacc[ni][r]*rl) | ((u32)f2bf(oacc[ni][r+1]*rl) << 16);
    }
  #pragma unroll
  for (int pass = 0; pass < 2; pass++){
    int qr = pass*8 + (lane >> 3);
    int d0 = (lane & 7)*8;
    bf16x8 row = *(const bf16x8*)((const char*)Ps[wid] + ((qr*128 + d0*2) ^ ((qr & 7) << 4)));
    *(bf16x8*)(AO + base + (size_t)(qw + qr)*DM + d0) = row;
  }
}

// ---------------- launch ----------------
extern "C" void kernel_launch(void* const* d_in, const int* in_sizes, int n_in,
                              void* d_out, int out_size, void* d_ws, size_t ws_size,
                              hipStream_t stream){
  const float* x   = (const float*)d_in[0];
  const float* Wq  = (const float*)d_in[1];
  const float* Wk  = (const float*)d_in[2];
  const float* Wv  = (const float*)d_in[3];
  const float* Wo  = (const float*)d_in[4];
  const int*   pos = (const int*)d_in[5];
  float* out = (float*)d_out;

  const size_t NEED = (size_t)40 << 20;
  if (ws_size < NEED){
    hipMemsetAsync(d_out, 0x7f, (size_t)out_size * sizeof(float), stream);
    return;
  }

  char* ws = (char*)d_ws;
  u16* xb = (u16*)(ws);
  u16* Wb = (u16*)(ws + ((size_t)8  << 20));
  u16* Qb = (u16*)(ws + ((size_t)16 << 20));
  u16* Kb = (u16*)(ws + ((size_t)24 << 20));
  u16* Vb = (u16*)(ws + ((size_t)32 << 20));
  u16* AO = xb;

  k_cast_x<<<4096, 256, 0, stream>>>(x, xb);
  k_cast_w<<<dim3(1024, 4), 256, 0, stream>>>(Wq, Wk, Wv, Wo, Wb);
  k_gemm_qkv<<<dim3(8, 32, 3), 256, 0, stream>>>(xb, Wb, Qb, Kb, Vb);
  k_rope<<<dim3(8192, 2), 256, 0, stream>>>(Qb, Kb, pos);
  k_attn<<<dim3(32, 16, 2), 256, 0, stream>>>(Qb, Kb, Vb, AO);
  k_gemm_out<<<dim3(8, 32), 256, 0, stream>>>(AO, Wb + ((size_t)3 << 20), out);
}

// Round 4
// 178.065 us; speedup vs baseline: 1.3439x; 1.2007x over previous
//
#include <hip/hip_runtime.h>

#define DM 1024
#define NH 16
#define DK 64
#define BB 2
#define SS 2048

typedef unsigned short u16;
typedef unsigned int   u32;
typedef __bf16 bf16x8 __attribute__((ext_vector_type(8)));
typedef float  f32x4  __attribute__((ext_vector_type(4)));

__device__ __forceinline__ u16 f2bf(float f){
  u32 u = __float_as_uint(f);
  u32 r = (u + 0x7FFFu + ((u >> 16) & 1u)) >> 16;   // RNE
  return (u16)r;
}
__device__ __forceinline__ float bf2f(u16 v){ return __uint_as_float(((u32)v) << 16); }

// packed bf16 convert: low16 = bf16(lo), high16 = bf16(hi), RNE
__device__ __forceinline__ u32 cvtpk(float lo, float hi){
  u32 r;
  asm volatile("v_cvt_pk_bf16_f32 %0, %1, %2" : "=v"(r) : "v"(lo), "v"(hi));
  return r;
}

__device__ __forceinline__ void gl16(const void* g, void* l){
  __builtin_amdgcn_global_load_lds((const __attribute__((address_space(1))) u32*)g,
                                   (__attribute__((address_space(3))) u32*)l, 16, 0, 0);
}
__device__ __forceinline__ f32x4 mfma16(bf16x8 a, bf16x8 b, f32x4 c){
  return __builtin_amdgcn_mfma_f32_16x16x32_bf16(a, b, c, 0, 0, 0);
}

// ---------------- casts ----------------
__global__ void k_cast_x(const float* __restrict__ s, u16* __restrict__ d){
  int i = (blockIdx.x*256 + threadIdx.x)*4;
  float4 v = *(const float4*)(s+i);
  uint2 t; t.x = cvtpk(v.x, v.y); t.y = cvtpk(v.z, v.w);
  *(uint2*)(d+i) = t;
}

__global__ void k_cast_w(const float* a, const float* b, const float* c, const float* dd,
                         u16* __restrict__ dst){
  const float* srcs[4] = {a,b,c,dd};
  const float* s = srcs[blockIdx.y];
  u16* o = dst + ((size_t)blockIdx.y << 20);
  int i = (blockIdx.x*256 + threadIdx.x)*4;
  float4 v = *(const float4*)(s+i);
  uint2 t; t.x = cvtpk(v.x, v.y); t.y = cvtpk(v.z, v.w);
  *(uint2*)(o+i) = t;
}

// ---------------- GEMM core (unchanged, verified) ----------------
__device__ __forceinline__ void gemm_core(const u16* __restrict__ A, const u16* __restrict__ Bw,
                                          u16* As, u16* Bs, f32x4 (&acc)[4][4]){
  const int tid = threadIdx.x, lane = tid & 63, wid = tid >> 6;
  const int m0 = blockIdx.y * 128, n0 = blockIdx.x * 128;
  const int wm = (wid >> 1) * 64, wn = (wid & 1) * 64;
  for (int k0 = 0; k0 < DM; k0 += 64){
    __syncthreads();
    #pragma unroll
    for (int i = 0; i < 4; i++){
      int row = i*32 + (tid >> 3);
      int cb  = (tid & 7) * 8;
      gl16(A  + (size_t)(m0+row)*DM + k0 + cb, (char*)As + i*4096 + tid*16);
      gl16(Bw + (size_t)(n0+row)*DM + k0 + cb, (char*)Bs + i*4096 + tid*16);
    }
    __syncthreads();
    #pragma unroll
    for (int kk = 0; kk < 2; kk++){
      const int co = kk*64 + (lane >> 4) * 16;
      bf16x8 af[4], bfr[4];
      #pragma unroll
      for (int mi = 0; mi < 4; mi++)
        af[mi] = *(const bf16x8*)((const char*)As + (wm + mi*16 + (lane & 15))*128 + co);
      #pragma unroll
      for (int ni = 0; ni < 4; ni++)
        bfr[ni] = *(const bf16x8*)((const char*)Bs + (wn + ni*16 + (lane & 15))*128 + co);
      #pragma unroll
      for (int mi = 0; mi < 4; mi++)
        #pragma unroll
        for (int ni = 0; ni < 4; ni++)
          acc[mi][ni] = mfma16(af[mi], bfr[ni], acc[mi][ni]);
    }
  }
}

__global__ __launch_bounds__(256) void k_gemm_qkv(const u16* __restrict__ xb, const u16* __restrict__ Wb,
                                                  u16* __restrict__ Qb, u16* __restrict__ Kb,
                                                  u16* __restrict__ Vb){
  __shared__ __align__(16) u16 As[8192];
  __shared__ __align__(16) u16 Bs[8192];
  const int z = blockIdx.z;
  const u16* Bw = Wb + ((size_t)z << 20);
  u16* C = (z == 0) ? Qb : ((z == 1) ? Kb : Vb);
  f32x4 acc[4][4] = {};
  gemm_core(xb, Bw, As, Bs, acc);
  const int lane = threadIdx.x & 63, wid = threadIdx.x >> 6;
  const int m0 = blockIdx.y*128 + (wid >> 1)*64, n0 = blockIdx.x*128 + (wid & 1)*64;
  #pragma unroll
  for (int mi = 0; mi < 4; mi++)
    #pragma unroll
    for (int ni = 0; ni < 4; ni++)
      #pragma unroll
      for (int r = 0; r < 4; r++){
        int m = m0 + mi*16 + (lane >> 4)*4 + r;
        int n = n0 + ni*16 + (lane & 15);
        C[(size_t)m*DM + n] = f2bf(acc[mi][ni][r]);
      }
}

__global__ __launch_bounds__(256) void k_gemm_out(const u16* __restrict__ AO, const u16* __restrict__ Wo,
                                                  float* __restrict__ Co){
  __shared__ __align__(16) u16 As[8192];
  __shared__ __align__(16) u16 Bs[8192];
  f32x4 acc[4][4] = {};
  gemm_core(AO, Wo, As, Bs, acc);
  const int lane = threadIdx.x & 63, wid = threadIdx.x >> 6;
  const int m0 = blockIdx.y*128 + (wid >> 1)*64, n0 = blockIdx.x*128 + (wid & 1)*64;
  #pragma unroll
  for (int mi = 0; mi < 4; mi++)
    #pragma unroll
    for (int ni = 0; ni < 4; ni++)
      #pragma unroll
      for (int r = 0; r < 4; r++){
        int m = m0 + mi*16 + (lane >> 4)*4 + r;
        int n = n0 + ni*16 + (lane & 15);
        Co[(size_t)m*DM + n] = acc[mi][ni][r];
      }
}

// ---------------- RoPE (unchanged, verified) ----------------
__global__ void k_rope(u16* __restrict__ Q, u16* __restrict__ K, const int* __restrict__ pos){
  int p = blockIdx.x*256 + threadIdx.x;
  int row = p >> 9;
  int j = p & 31;
  float pf = (float)pos[row & (SS-1)];
  float inv = exp2f(-0.4152410118609203f * (float)j);
  float s, c;
  sincosf(pf * inv, &s, &c);
  u32* T = (u32*)(blockIdx.y ? K : Q);
  u32 e = T[p];
  float x0 = bf2f((u16)(e & 0xffff)), x1 = bf2f((u16)(e >> 16));
  float o0 = x0*c - x1*s;
  float o1 = x0*s + x1*c;
  T[p] = (u32)f2bf(o0) | ((u32)f2bf(o1) << 16);
}

// ---------------- flash attention, causal ----------------
// R4: (1) balanced qt remap: co-resident blocks {i,i+256,i+512,i+768} differ in
// (blockIdx.y>>3)&1 -> complementary qt -> every CU gets exactly 66 tile-iters.
// (2) raw-domain max + defer-max (THR=8 log2-units): skip cross-lane max shuffles
// and O-rescale unless the tile max grew past m+THR. (3) per-lane lsum partials,
// reduced once in epilogue. (4) v_cvt_pk_bf16_f32 for all f32->bf16 packing.
__global__ __launch_bounds__(256) void k_attn(const u16* __restrict__ Q, const u16* __restrict__ K,
                                              const u16* __restrict__ V, u16* __restrict__ AO){
  __shared__ __align__(16) u16 Ks[2][64*64];
  __shared__ __align__(16) u16 Vt[2][64*64];
  __shared__ __align__(16) u16 Ps[4][16*64];
  const int tid = threadIdx.x, lane = tid & 63, wid = tid >> 6;
  const int xq = blockIdx.x;
  const int qt = ((blockIdx.y >> 3) & 1) ? ((int)gridDim.x - 1 - xq) : xq;  // balanced pairing
  const int h = blockIdx.y, b = blockIdx.z;
  const int q0 = qt*64, qw = q0 + wid*16;
  const size_t base = ((size_t)b*SS)*DM + (size_t)h*DK;
  const int ql = lane & 15, lg = lane >> 4;

  const u16* qptr = Q + base + (size_t)(qw + ql)*DM + lg*8;
  bf16x8 qf0 = *(const bf16x8*)(qptr);
  bf16x8 qf1 = *(const bf16x8*)(qptr + 32);

  f32x4 oacc[4] = {};
  float m = -3e38f, lsum = 0.f;                    // m in RAW score units; lsum per-lane partial
  const float SC = 0.18033688011112042f;           // (1/sqrt(64)) * log2(e)
  const float THR = 8.0f / SC;                     // defer-max threshold in raw units

  const int dbase = (tid >> 5)*8, kvl = (tid & 31)*2;

  // ---- prologue: stage tile 0 ----
  #pragma unroll
  for (int i = 0; i < 2; i++){
    int L = i*4096 + tid*16;
    int kv = L >> 7;
    int inner = (L & 127) ^ ((kv & 7) << 4);
    gl16(K + base + (size_t)kv*DM + (inner >> 1), (char*)Ks[0] + L);
  }
  {
    const u16* vsrc = V + base + (size_t)kvl*DM + dbase;
    bf16x8 r0 = *(const bf16x8*)(vsrc);
    bf16x8 r1 = *(const bf16x8*)(vsrc + DM);
    const u16* p0 = (const u16*)&r0; const u16* p1 = (const u16*)&r1;
    #pragma unroll
    for (int j = 0; j < 8; j++){
      int d = dbase + j;
      int byteoff = (d*128 + kvl*2) ^ ((d & 7) << 4);
      *(u32*)((char*)Vt[0] + byteoff) = (u32)p0[j] | ((u32)p1[j] << 16);
    }
  }
  __syncthreads();

  int cur = 0;
  for (int kt = 0; kt <= qt; kt++){
    const int kv0 = kt*64;
    const bool more = (kt < qt);
    bf16x8 vr0, vr1;
    if (more){
      const int kn0 = kv0 + 64;
      #pragma unroll
      for (int i = 0; i < 2; i++){
        int L = i*4096 + tid*16;
        int kv = L >> 7;
        int inner = (L & 127) ^ ((kv & 7) << 4);
        gl16(K + base + (size_t)(kn0+kv)*DM + (inner >> 1), (char*)Ks[cur^1] + L);
      }
      const u16* vsrc = V + base + (size_t)(kn0+kvl)*DM + dbase;
      vr0 = *(const bf16x8*)(vsrc);
      vr1 = *(const bf16x8*)(vsrc + DM);
    }

    // QK^T swapped: sf[f][r] = S_raw[kv0 + f*16 + lg*4 + r][qw + ql]
    f32x4 sf[4] = {};
    #pragma unroll
    for (int kk = 0; kk < 2; kk++){
      const int co = kk*64 + lg*16;
      #pragma unroll
      for (int f = 0; f < 4; f++){
        int kvr = f*16 + ql;
        bf16x8 kf = *(const bf16x8*)((const char*)Ks[cur] + ((kvr*128 + co) ^ ((kvr & 7) << 4)));
        sf[f] = mfma16(kf, kk ? qf1 : qf0, sf[f]);
      }
    }

    // mask (diagonal tile only), raw domain
    if (kt == qt){
      const int qa = qw + ql;
      #pragma unroll
      for (int f = 0; f < 4; f++)
        #pragma unroll
        for (int r = 0; r < 4; r++){
          int kva = kv0 + f*16 + lg*4 + r;
          sf[f][r] = (kva <= qa) ? sf[f][r] : -3e38f;
        }
    }

    // lane-local max (raw)
    float mx01 = fmaxf(fmaxf(sf[0][0], sf[0][1]), fmaxf(sf[0][2], sf[0][3]));
    float mx23 = fmaxf(fmaxf(sf[1][0], sf[1][1]), fmaxf(sf[1][2], sf[1][3]));
    float mx45 = fmaxf(fmaxf(sf[2][0], sf[2][1]), fmaxf(sf[2][2], sf[2][3]));
    float mx67 = fmaxf(fmaxf(sf[3][0], sf[3][1]), fmaxf(sf[3][2], sf[3][3]));
    float mx = fmaxf(fmaxf(mx01, mx23), fmaxf(mx45, mx67));

    // defer-max: only pay shuffles + rescale when the max actually grew
    if (!__all(mx <= m + THR)){
      mx = fmaxf(mx, __shfl_xor(mx, 16));
      mx = fmaxf(mx, __shfl_xor(mx, 32));
      const float mn = fmaxf(m, mx);
      const float alpha = exp2f((m - mn)*SC);
      #pragma unroll
      for (int ni = 0; ni < 4; ni++) oacc[ni] *= alpha;
      lsum *= alpha;
      m = mn;
    }

    // P = exp2(sf*SC - m*SC), per-lane partial sum; pack pairs via cvt_pk
    const float nms = -m*SC;
    float p[4][4];
    float psum = 0.f;
    #pragma unroll
    for (int f = 0; f < 4; f++)
      #pragma unroll
      for (int r = 0; r < 4; r++){
        p[f][r] = exp2f(fmaf(sf[f][r], SC, nms));
        psum += p[f][r];
      }
    lsum += psum;

    #pragma unroll
    for (int f = 0; f < 4; f++)
      #pragma unroll
      for (int r = 0; r < 4; r += 2){
        int kv = f*16 + lg*4 + r;
        int byteoff = (ql*128 + kv*2) ^ ((ql & 7) << 4);
        *(u32*)((char*)Ps[wid] + byteoff) = cvtpk(p[f][r], p[f][r+1]);
      }

    // PV swapped: oacc[ni][r] = O[d = ni*16 + lg*4 + r][q = ql]
    #pragma unroll
    for (int kk = 0; kk < 2; kk++){
      bf16x8 pf = *(const bf16x8*)((const char*)Ps[wid] +
                    ((ql*128 + kk*64 + lg*16) ^ ((ql & 7) << 4)));
      #pragma unroll
      for (int ni = 0; ni < 4; ni++){
        int d = ni*16 + ql;
        bf16x8 vf = *(const bf16x8*)((const char*)Vt[cur] +
                      ((d*128 + kk*64 + lg*16) ^ ((d & 7) << 4)));
        oacc[ni] = mfma16(vf, pf, oacc[ni]);
      }
    }

    if (more){
      const u16* p0 = (const u16*)&vr0; const u16* p1 = (const u16*)&vr1;
      #pragma unroll
      for (int j = 0; j < 8; j++){
        int d = dbase + j;
        int byteoff = (d*128 + kvl*2) ^ ((d & 7) << 4);
        *(u32*)((char*)Vt[cur^1] + byteoff) = (u32)p0[j] | ((u32)p1[j] << 16);
      }
    }
    __syncthreads();
    cur ^= 1;
  }

  // epilogue: reduce per-lane lsum partials across the 4 lanes of each q-row
  lsum += __shfl_xor(lsum, 16);
  lsum += __shfl_xor(lsum, 32);
  const float rl = 1.0f / lsum;
  #pragma unroll
  for (int ni = 0; ni < 4; ni++)
    #pragma unroll
    for (int r = 0; r < 4; r += 2){
      int d = ni*16 + lg*4 + r;
      int byteoff = (ql*128 + d*2) ^ ((ql & 7) << 4);
      *(u32*)((char*)Ps[wid] + byteoff) = cvtpk(oacc[ni][r]*rl, oacc[ni][r+1]*rl);
    }
  #pragma unroll
  for (int pass = 0; pass < 2; pass++){
    int qr = pass*8 + (lane >> 3);
    int d0 = (lane & 7)*8;
    bf16x8 row = *(const bf16x8*)((const char*)Ps[wid] + ((qr*128 + d0*2) ^ ((qr & 7) << 4)));
    *(bf16x8*)(AO + base + (size_t)(qw + qr)*DM + d0) = row;
  }
}

// ---------------- launch ----------------
extern "C" void kernel_launch(void* const* d_in, const int* in_sizes, int n_in,
                              void* d_out, int out_size, void* d_ws, size_t ws_size,
                              hipStream_t stream){
  const float* x   = (const float*)d_in[0];
  const float* Wq  = (const float*)d_in[1];
  const float* Wk  = (const float*)d_in[2];
  const float* Wv  = (const float*)d_in[3];
  const float* Wo  = (const float*)d_in[4];
  const int*   pos = (const int*)d_in[5];
  float* out = (float*)d_out;

  const size_t NEED = (size_t)40 << 20;
  if (ws_size < NEED){
    hipMemsetAsync(d_out, 0x7f, (size_t)out_size * sizeof(float), stream);
    return;
  }

  char* ws = (char*)d_ws;
  u16* xb = (u16*)(ws);
  u16* Wb = (u16*)(ws + ((size_t)8  << 20));
  u16* Qb = (u16*)(ws + ((size_t)16 << 20));
  u16* Kb = (u16*)(ws + ((size_t)24 << 20));
  u16* Vb = (u16*)(ws + ((size_t)32 << 20));
  u16* AO = xb;

  k_cast_x<<<4096, 256, 0, stream>>>(x, xb);
  k_cast_w<<<dim3(1024, 4), 256, 0, stream>>>(Wq, Wk, Wv, Wo, Wb);
  k_gemm_qkv<<<dim3(8, 32, 3), 256, 0, stream>>>(xb, Wb, Qb, Kb, Vb);
  k_rope<<<dim3(8192, 2), 256, 0, stream>>>(Qb, Kb, pos);
  k_attn<<<dim3(32, 16, 2), 256, 0, stream>>>(Qb, Kb, Vb, AO);
  k_gemm_out<<<dim3(8, 32), 256, 0, stream>>>(AO, Wb + ((size_t)3 << 20), out);
}

// Round 5
// 168.839 us; speedup vs baseline: 1.4173x; 1.0546x over previous
//
#include <hip/hip_runtime.h>

#define DM 1024
#define NH 16
#define DK 64
#define BB 2
#define SS 2048

typedef unsigned short u16;
typedef unsigned int   u32;
typedef __bf16 bf16x8 __attribute__((ext_vector_type(8)));
typedef float  f32x4  __attribute__((ext_vector_type(4)));

__device__ __forceinline__ u16 f2bf(float f){
  u32 u = __float_as_uint(f);
  u32 r = (u + 0x7FFFu + ((u >> 16) & 1u)) >> 16;   // RNE
  return (u16)r;
}
__device__ __forceinline__ float bf2f(u16 v){ return __uint_as_float(((u32)v) << 16); }

// packed bf16 convert: low16 = bf16(lo), high16 = bf16(hi), RNE
__device__ __forceinline__ u32 cvtpk(float lo, float hi){
  u32 r;
  asm volatile("v_cvt_pk_bf16_f32 %0, %1, %2" : "=v"(r) : "v"(lo), "v"(hi));
  return r;
}

__device__ __forceinline__ void gl16(const void* g, void* l){
  __builtin_amdgcn_global_load_lds((const __attribute__((address_space(1))) u32*)g,
                                   (__attribute__((address_space(3))) u32*)l, 16, 0, 0);
}
__device__ __forceinline__ f32x4 mfma16(bf16x8 a, bf16x8 b, f32x4 c){
  return __builtin_amdgcn_mfma_f32_16x16x32_bf16(a, b, c, 0, 0, 0);
}

// ---------------- merged cast (x + 4 weights), 4 f32/thread ----------------
__global__ void k_cast(const float* __restrict__ x,  const float* __restrict__ wq,
                       const float* __restrict__ wk, const float* __restrict__ wv,
                       const float* __restrict__ wo, u16* __restrict__ xb,
                       u16* __restrict__ wb){
  int e = blockIdx.x*1024 + threadIdx.x*4;     // 8M elems total: 4M x + 4x1M weights
  int r = e >> 20;                              // 0..3 = x, 4..7 = weights
  const float* s; u16* d; int local;
  if (r < 4){ s = x; d = xb; local = e; }
  else {
    const float* ws[4] = {wq, wk, wv, wo};
    int w = r - 4;
    local = e & 0xFFFFF;
    s = ws[w]; d = wb + ((size_t)w << 20);
  }
  float4 v = *(const float4*)(s + local);
  uint2 t; t.x = cvtpk(v.x, v.y); t.y = cvtpk(v.z, v.w);
  *(uint2*)(d + local) = t;
}

// ---------------- GEMM core (unchanged, verified) ----------------
__device__ __forceinline__ void gemm_core(const u16* __restrict__ A, const u16* __restrict__ Bw,
                                          u16* As, u16* Bs, f32x4 (&acc)[4][4]){
  const int tid = threadIdx.x, lane = tid & 63, wid = tid >> 6;
  const int m0 = blockIdx.y * 128, n0 = blockIdx.x * 128;
  const int wm = (wid >> 1) * 64, wn = (wid & 1) * 64;
  for (int k0 = 0; k0 < DM; k0 += 64){
    __syncthreads();
    #pragma unroll
    for (int i = 0; i < 4; i++){
      int row = i*32 + (tid >> 3);
      int cb  = (tid & 7) * 8;
      gl16(A  + (size_t)(m0+row)*DM + k0 + cb, (char*)As + i*4096 + tid*16);
      gl16(Bw + (size_t)(n0+row)*DM + k0 + cb, (char*)Bs + i*4096 + tid*16);
    }
    __syncthreads();
    #pragma unroll
    for (int kk = 0; kk < 2; kk++){
      const int co = kk*64 + (lane >> 4) * 16;
      bf16x8 af[4], bfr[4];
      #pragma unroll
      for (int mi = 0; mi < 4; mi++)
        af[mi] = *(const bf16x8*)((const char*)As + (wm + mi*16 + (lane & 15))*128 + co);
      #pragma unroll
      for (int ni = 0; ni < 4; ni++)
        bfr[ni] = *(const bf16x8*)((const char*)Bs + (wn + ni*16 + (lane & 15))*128 + co);
      #pragma unroll
      for (int mi = 0; mi < 4; mi++)
        #pragma unroll
        for (int ni = 0; ni < 4; ni++)
          acc[mi][ni] = mfma16(af[mi], bfr[ni], acc[mi][ni]);
    }
  }
}

__global__ __launch_bounds__(256) void k_gemm_qkv(const u16* __restrict__ xb, const u16* __restrict__ Wb,
                                                  u16* __restrict__ Qb, u16* __restrict__ Kb,
                                                  u16* __restrict__ Vb){
  __shared__ __align__(16) u16 As[8192];
  __shared__ __align__(16) u16 Bs[8192];
  const int z = blockIdx.z;
  const u16* Bw = Wb + ((size_t)z << 20);
  u16* C = (z == 0) ? Qb : ((z == 1) ? Kb : Vb);
  f32x4 acc[4][4] = {};
  gemm_core(xb, Bw, As, Bs, acc);
  const int lane = threadIdx.x & 63, wid = threadIdx.x >> 6;
  const int m0 = blockIdx.y*128 + (wid >> 1)*64, n0 = blockIdx.x*128 + (wid & 1)*64;
  #pragma unroll
  for (int mi = 0; mi < 4; mi++)
    #pragma unroll
    for (int ni = 0; ni < 4; ni++)
      #pragma unroll
      for (int r = 0; r < 4; r++){
        int m = m0 + mi*16 + (lane >> 4)*4 + r;
        int n = n0 + ni*16 + (lane & 15);
        C[(size_t)m*DM + n] = f2bf(acc[mi][ni][r]);
      }
}

__global__ __launch_bounds__(256) void k_gemm_out(const u16* __restrict__ AO, const u16* __restrict__ Wo,
                                                  float* __restrict__ Co){
  __shared__ __align__(16) u16 As[8192];
  __shared__ __align__(16) u16 Bs[8192];
  f32x4 acc[4][4] = {};
  gemm_core(AO, Wo, As, Bs, acc);
  const int lane = threadIdx.x & 63, wid = threadIdx.x >> 6;
  const int m0 = blockIdx.y*128 + (wid >> 1)*64, n0 = blockIdx.x*128 + (wid & 1)*64;
  #pragma unroll
  for (int mi = 0; mi < 4; mi++)
    #pragma unroll
    for (int ni = 0; ni < 4; ni++)
      #pragma unroll
      for (int r = 0; r < 4; r++){
        int m = m0 + mi*16 + (lane >> 4)*4 + r;
        int n = n0 + ni*16 + (lane & 15);
        Co[(size_t)m*DM + n] = acc[mi][ni][r];
      }
}

// ---------------- RoPE (unchanged, verified) ----------------
__global__ void k_rope(u16* __restrict__ Q, u16* __restrict__ K, const int* __restrict__ pos){
  int p = blockIdx.x*256 + threadIdx.x;
  int row = p >> 9;
  int j = p & 31;
  float pf = (float)pos[row & (SS-1)];
  float inv = exp2f(-0.4152410118609203f * (float)j);
  float s, c;
  sincosf(pf * inv, &s, &c);
  u32* T = (u32*)(blockIdx.y ? K : Q);
  u32 e = T[p];
  float x0 = bf2f((u16)(e & 0xffff)), x1 = bf2f((u16)(e >> 16));
  float o0 = x0*c - x1*s;
  float o1 = x0*s + x1*c;
  T[p] = (u32)f2bf(o0) | ((u32)f2bf(o1) << 16);
}

// ---------------- flash attention, causal, 8-wave QBLK=128 ----------------
// R5: 512-thread blocks; 8 waves x 16 q-rows = 128-q tile share each 64-kv staged
// tile -> staging bytes, staging VALU, and barrier rounds per unit work halve.
// Balance: co-resident blocks {i, i+256} differ in z -> qb = z ? 15-x : x gives
// every CU exactly 34 tile-iters. Waves whose q-rows lie fully left of the kv
// tile skip compute (barriers still honored). s_setprio(1) around MFMA clusters.
__global__ __launch_bounds__(512) void k_attn(const u16* __restrict__ Q, const u16* __restrict__ K,
                                              const u16* __restrict__ V, u16* __restrict__ AO){
  __shared__ __align__(16) u16 Ks[2][64*64];
  __shared__ __align__(16) u16 Vt[2][64*64];
  __shared__ __align__(16) u16 Ps[8][16*64];
  const int tid = threadIdx.x, lane = tid & 63, wid = tid >> 6;
  const int b = blockIdx.z, h = blockIdx.y;
  const int qb = b ? (15 - (int)blockIdx.x) : (int)blockIdx.x;   // balanced pairing
  const int qw = qb*128 + wid*16;
  const size_t base = ((size_t)b*SS)*DM + (size_t)h*DK;
  const int ql = lane & 15, lg = lane >> 4;
  const int NT = 2*qb + 2;

  const u16* qptr = Q + base + (size_t)(qw + ql)*DM + lg*8;
  bf16x8 qf0 = *(const bf16x8*)(qptr);
  bf16x8 qf1 = *(const bf16x8*)(qptr + 32);

  f32x4 oacc[4] = {};
  float m = -3e38f, lsum = 0.f;                 // raw-domain running max; per-lane partial sum
  const float SC = 0.18033688011112042f;        // (1/sqrt(64)) * log2(e)
  const float THR = 8.0f / SC;

  // staging coords: K = 1 gl16/thread (8KB/512/16B); V = 4 d x 2 kv per thread
  const int skv = tid >> 3;
  const int sin = ((tid & 7) * 16) ^ ((skv & 7) << 4);   // pre-swizzled source byte col
  const int kvl = (tid & 31)*2, dbase = (tid >> 5)*4;

  // ---- prologue: stage tile 0 ----
  gl16(K + base + (size_t)skv*DM + (sin >> 1), (char*)Ks[0] + tid*16);
  {
    const u16* vsrc = V + base + (size_t)kvl*DM + dbase;
    ushort4 r0 = *(const ushort4*)(vsrc);
    ushort4 r1 = *(const ushort4*)(vsrc + DM);
    const u16 a0[4] = {r0.x, r0.y, r0.z, r0.w};
    const u16 a1[4] = {r1.x, r1.y, r1.z, r1.w};
    #pragma unroll
    for (int j = 0; j < 4; j++){
      int d = dbase + j;
      int byteoff = (d*128 + kvl*2) ^ ((d & 7) << 4);
      *(u32*)((char*)Vt[0] + byteoff) = (u32)a0[j] | ((u32)a1[j] << 16);
    }
  }
  __syncthreads();

  int cur = 0;
  for (int kt = 0; kt < NT; kt++){
    const int kv0 = kt*64;
    const bool more = (kt < NT-1);
    ushort4 vr0, vr1;
    if (more){
      const int kn0 = kv0 + 64;
      gl16(K + base + (size_t)(kn0+skv)*DM + (sin >> 1), (char*)Ks[cur^1] + tid*16);
      const u16* vsrc = V + base + (size_t)(kn0+kvl)*DM + dbase;
      vr0 = *(const ushort4*)(vsrc);
      vr1 = *(const ushort4*)(vsrc + DM);
    }

    const bool active = (kv0 <= qw + 15);       // wave-uniform
    if (active){
      // QK^T swapped: sf[f][r] = S_raw[kv0 + f*16 + lg*4 + r][qw + ql]
      f32x4 sf[4] = {};
      __builtin_amdgcn_s_setprio(1);
      #pragma unroll
      for (int kk = 0; kk < 2; kk++){
        const int co = kk*64 + lg*16;
        #pragma unroll
        for (int f = 0; f < 4; f++){
          int kvr = f*16 + ql;
          bf16x8 kf = *(const bf16x8*)((const char*)Ks[cur] + ((kvr*128 + co) ^ ((kvr & 7) << 4)));
          sf[f] = mfma16(kf, kk ? qf1 : qf0, sf[f]);
        }
      }
      __builtin_amdgcn_s_setprio(0);

      if (kv0 + 63 > qw){                       // mask needed (partially diagonal)
        const int qa = qw + ql;
        #pragma unroll
        for (int f = 0; f < 4; f++)
          #pragma unroll
          for (int r = 0; r < 4; r++){
            int kva = kv0 + f*16 + lg*4 + r;
            sf[f][r] = (kva <= qa) ? sf[f][r] : -3e38f;
          }
      }

      float mx01 = fmaxf(fmaxf(sf[0][0], sf[0][1]), fmaxf(sf[0][2], sf[0][3]));
      float mx23 = fmaxf(fmaxf(sf[1][0], sf[1][1]), fmaxf(sf[1][2], sf[1][3]));
      float mx45 = fmaxf(fmaxf(sf[2][0], sf[2][1]), fmaxf(sf[2][2], sf[2][3]));
      float mx67 = fmaxf(fmaxf(sf[3][0], sf[3][1]), fmaxf(sf[3][2], sf[3][3]));
      float mx = fmaxf(fmaxf(mx01, mx23), fmaxf(mx45, mx67));

      if (!__all(mx <= m + THR)){               // defer-max
        mx = fmaxf(mx, __shfl_xor(mx, 16));
        mx = fmaxf(mx, __shfl_xor(mx, 32));
        const float mn = fmaxf(m, mx);
        const float alpha = exp2f((m - mn)*SC);
        #pragma unroll
        for (int ni = 0; ni < 4; ni++) oacc[ni] *= alpha;
        lsum *= alpha;
        m = mn;
      }

      const float nms = -m*SC;
      float p[4][4];
      float psum = 0.f;
      #pragma unroll
      for (int f = 0; f < 4; f++)
        #pragma unroll
        for (int r = 0; r < 4; r++){
          p[f][r] = exp2f(fmaf(sf[f][r], SC, nms));
          psum += p[f][r];
        }
      lsum += psum;

      #pragma unroll
      for (int f = 0; f < 4; f++)
        #pragma unroll
        for (int r = 0; r < 4; r += 2){
          int kv = f*16 + lg*4 + r;
          int byteoff = (ql*128 + kv*2) ^ ((ql & 7) << 4);
          *(u32*)((char*)Ps[wid] + byteoff) = cvtpk(p[f][r], p[f][r+1]);
        }

      // PV swapped: oacc[ni][r] = O[d = ni*16 + lg*4 + r][q = ql]
      __builtin_amdgcn_s_setprio(1);
      #pragma unroll
      for (int kk = 0; kk < 2; kk++){
        bf16x8 pf = *(const bf16x8*)((const char*)Ps[wid] +
                      ((ql*128 + kk*64 + lg*16) ^ ((ql & 7) << 4)));
        #pragma unroll
        for (int ni = 0; ni < 4; ni++){
          int d = ni*16 + ql;
          bf16x8 vf = *(const bf16x8*)((const char*)Vt[cur] +
                        ((d*128 + kk*64 + lg*16) ^ ((d & 7) << 4)));
          oacc[ni] = mfma16(vf, pf, oacc[ni]);
        }
      }
      __builtin_amdgcn_s_setprio(0);
    }

    if (more){
      const u16 a0[4] = {vr0.x, vr0.y, vr0.z, vr0.w};
      const u16 a1[4] = {vr1.x, vr1.y, vr1.z, vr1.w};
      #pragma unroll
      for (int j = 0; j < 4; j++){
        int d = dbase + j;
        int byteoff = (d*128 + kvl*2) ^ ((d & 7) << 4);
        *(u32*)((char*)Vt[cur^1] + byteoff) = (u32)a0[j] | ((u32)a1[j] << 16);
      }
    }
    __syncthreads();
    cur ^= 1;
  }

  // epilogue: reduce per-lane lsum partials, transpose O through LDS, store
  lsum += __shfl_xor(lsum, 16);
  lsum += __shfl_xor(lsum, 32);
  const float rl = 1.0f / lsum;
  #pragma unroll
  for (int ni = 0; ni < 4; ni++)
    #pragma unroll
    for (int r = 0; r < 4; r += 2){
      int d = ni*16 + lg*4 + r;
      int byteoff = (ql*128 + d*2) ^ ((ql & 7) << 4);
      *(u32*)((char*)Ps[wid] + byteoff) = cvtpk(oacc[ni][r]*rl, oacc[ni][r+1]*rl);
    }
  #pragma unroll
  for (int pass = 0; pass < 2; pass++){
    int qr = pass*8 + (lane >> 3);
    int d0 = (lane & 7)*8;
    bf16x8 row = *(const bf16x8*)((const char*)Ps[wid] + ((qr*128 + d0*2) ^ ((qr & 7) << 4)));
    *(bf16x8*)(AO + base + (size_t)(qw + qr)*DM + d0) = row;
  }
}

// ---------------- launch ----------------
extern "C" void kernel_launch(void* const* d_in, const int* in_sizes, int n_in,
                              void* d_out, int out_size, void* d_ws, size_t ws_size,
                              hipStream_t stream){
  const float* x   = (const float*)d_in[0];
  const float* Wq  = (const float*)d_in[1];
  const float* Wk  = (const float*)d_in[2];
  const float* Wv  = (const float*)d_in[3];
  const float* Wo  = (const float*)d_in[4];
  const int*   pos = (const int*)d_in[5];
  float* out = (float*)d_out;

  const size_t NEED = (size_t)40 << 20;
  if (ws_size < NEED){
    hipMemsetAsync(d_out, 0x7f, (size_t)out_size * sizeof(float), stream);
    return;
  }

  char* ws = (char*)d_ws;
  u16* xb = (u16*)(ws);
  u16* Wb = (u16*)(ws + ((size_t)8  << 20));
  u16* Qb = (u16*)(ws + ((size_t)16 << 20));
  u16* Kb = (u16*)(ws + ((size_t)24 << 20));
  u16* Vb = (u16*)(ws + ((size_t)32 << 20));
  u16* AO = xb;

  k_cast<<<8192, 256, 0, stream>>>(x, Wq, Wk, Wv, Wo, xb, Wb);
  k_gemm_qkv<<<dim3(8, 32, 3), 256, 0, stream>>>(xb, Wb, Qb, Kb, Vb);
  k_rope<<<dim3(8192, 2), 256, 0, stream>>>(Qb, Kb, pos);
  k_attn<<<dim3(16, 16, 2), 512, 0, stream>>>(Qb, Kb, Vb, AO);
  k_gemm_out<<<dim3(8, 32), 256, 0, stream>>>(AO, Wb + ((size_t)3 << 20), out);
}